// Round 10
// baseline (82.925 us; speedup 1.0000x reference)
//
#include <hip/hip_runtime.h>
#include <math.h>

#define BB 8
#define NN 512
#define FF 32
#define HH 64
#define NEG_BIG (-1.0e30f)

__device__ __forceinline__ float lane_bcast(float v, int l) {
    return __int_as_float(__builtin_amdgcn_readlane(__float_as_int(v), l));
}

// ---------------------------------------------------------------------------
// encode: h = relu(x@W_enc+b); zi = h@W_e1[:H]+b_e1 (folded); zj = h@W_e1[H:]
// grid 1024 x 256: block = 4 rows, wave qu owns row, lane hh owns column.
// ---------------------------------------------------------------------------
__global__ __launch_bounds__(256) void encode_kernel(
    const float* __restrict__ x, const float* __restrict__ W_enc,
    const float* __restrict__ b_enc, const float* __restrict__ W_e1,
    const float* __restrict__ b_e1,
    float* __restrict__ h, float* __restrict__ zi, float* __restrict__ zj)
{
    const int t = threadIdx.x;
    const int hh = t & 63;
    const int qu = __builtin_amdgcn_readfirstlane(t >> 6);
    const int gR = blockIdx.x * 4 + qu;           // 0..B*N-1

    const float xv = x[gR * FF + (hh & 31)];      // coalesced; lanes 32+ dup
    float acc = b_enc[hh];
#pragma unroll 8
    for (int k = 0; k < FF; ++k)
        acc = fmaf(lane_bcast(xv, k), W_enc[k * HH + hh], acc);
    const float hval = fmaxf(acc, 0.f);
    h[gR * HH + hh] = hval;

    float z1 = b_e1[hh], z2 = 0.f;
#pragma unroll 8
    for (int k = 0; k < HH; ++k) {
        const float hk = lane_bcast(hval, k);
        z1 = fmaf(hk, W_e1[k * HH + hh], z1);
        z2 = fmaf(hk, W_e1[(HH + k) * HH + hh], z2);
    }
    zi[gR * HH + hh] = z1;
    zj[gR * HH + hh] = z2;
}

// ---------------------------------------------------------------------------
// adjlayer<MODE>: one GNN layer, 512 blocks x 256 thr (2 blocks/CU), block =
// (b, 8 rows), wave w owns j-quarter [128w,128w+128) / row-pair {2w,2w+1}.
// MODE 0: compute adjacency in-register (softmax'd), store for layer 2, and
//         consume it directly from registers in phase A.
// MODE 1: load adjacency tile from global; fold readout partial at the end.
// All GEMM broadcasts are v_readlane from per-lane register vectors (VALU,
// per-SIMD pipe) -- NO wave-uniform LDS reads anywhere (per-CU LDS pipe was
// the invariant ~10us/layer cost of R7/R8/R9).
// LDS: zjs[512][17] staging (MODE 0), unioned with red/gpart partial buffers
// (barrier-separated), + mml/hol row caches.
// ---------------------------------------------------------------------------
template <int MODE>
__global__ __launch_bounds__(256, 2) void adjlayer_kernel(
    const float* __restrict__ zi, const float* __restrict__ zj,
    const float* __restrict__ We2, const float* __restrict__ be2,
    float* __restrict__ adjw, const float* __restrict__ h_in,
    const float* __restrict__ Wmsg, const float* __restrict__ bmsg,
    const float* __restrict__ Wih, const float* __restrict__ bih,
    const float* __restrict__ Whh, const float* __restrict__ bhh,
    float* __restrict__ h_out, float* __restrict__ partial)
{
    const int b  = blockIdx.x >> 6;
    const int i0 = (blockIdx.x & 63) << 3;        // 8 rows
    const int t  = threadIdx.x;
    const int tj = t & 63;                        // lane: j-pos / column
    const int w  = __builtin_amdgcn_readfirstlane(t >> 6);   // 0..3
    const int gR0 = b * NN + i0;

    __shared__ float smem[NN * 17];               // 34.8 KB union buffer
    __shared__ float mml[8][66];
    __shared__ float hol[8][66];
    __shared__ float redm[4][8];
    __shared__ float reds[4][8];

    float (*zjs)[17] = (float (*)[17])smem;
#define RED(p, r, c)       smem[(((p) * 8) + (r)) * 66 + (c)]
#define GP(h2, k2, r, g, c) smem[((((((h2) * 2 + (k2)) * 8) + (r)) * 3 + (g)) * 66) + (c)]

    const int r0 = 2 * w, r1 = 2 * w + 1;
    // own-row h cache (read by phase C half=1 and finalize, after barriers)
    hol[r0][tj] = h_in[(size_t)(gR0 + r0) * HH + tj];
    hol[r1][tj] = h_in[(size_t)(gR0 + r1) * HH + tj];

    //=== adjacency: in registers va[r][c], lane tj = j = 128w + 64c + tj ====
    float va[8][2];
    if (MODE == 0) {
        float zir[8];
#pragma unroll
        for (int r = 0; r < 8; ++r) zir[r] = zi[(size_t)(gR0 + r) * HH + tj];
        const float wv = We2[tj];
        const float bias2 = be2[0];
        float acc[8][2];
#pragma unroll
        for (int r = 0; r < 8; ++r) { acc[r][0] = bias2; acc[r][1] = bias2; }

        for (int kp = 0; kp < 4; ++kp) {
            __syncthreads();
#pragma unroll
            for (int u = 0; u < 8; ++u) {       // stage zj[:, 16-k slice]
                const int i4 = t + u * 256;
                const int row = i4 >> 2, c4 = i4 & 3;
                *(float4*)&zjs[row][c4 * 4] =
                    ((const float4*)(zj + (size_t)(b * NN + row) * HH))[kp * 4 + c4];
            }
            __syncthreads();
            const int j0 = 128 * w + tj, j1 = j0 + 64;
#pragma unroll
            for (int kk = 0; kk < 16; ++kk) {
                const int k = (kp << 4) + kk;
                const float wk = lane_bcast(wv, k);
                const float zj0 = zjs[j0][kk];
                const float zj1 = zjs[j1][kk];
#pragma unroll
                for (int r = 0; r < 8; ++r) {
                    const float zv = lane_bcast(zir[r], k);
                    acc[r][0] = fmaf(fmaxf(zv + zj0, 0.f), wk, acc[r][0]);
                    acc[r][1] = fmaf(fmaxf(zv + zj1, 0.f), wk, acc[r][1]);
                }
            }
        }
        // diag mask
#pragma unroll
        for (int r = 0; r < 8; ++r)
#pragma unroll
            for (int c = 0; c < 2; ++c)
                if (128 * w + 64 * c + tj == i0 + r) acc[r][c] = NEG_BIG;

        // softmax: wave-reduce + tiny cross-wave LDS reduce
#pragma unroll
        for (int r = 0; r < 8; ++r) {
            float m = fmaxf(acc[r][0], acc[r][1]);
#pragma unroll
            for (int off = 32; off >= 1; off >>= 1) m = fmaxf(m, __shfl_xor(m, off));
            if (tj == 0) redm[w][r] = m;
        }
        __syncthreads();
        float M[8];
#pragma unroll
        for (int r = 0; r < 8; ++r)
            M[r] = fmaxf(fmaxf(redm[0][r], redm[1][r]),
                         fmaxf(redm[2][r], redm[3][r]));
#pragma unroll
        for (int r = 0; r < 8; ++r) {
            const float e0 = __expf(acc[r][0] - M[r]);
            const float e1 = __expf(acc[r][1] - M[r]);
            va[r][0] = e0; va[r][1] = e1;
            float s = e0 + e1;
#pragma unroll
            for (int off = 32; off >= 1; off >>= 1) s += __shfl_xor(s, off);
            if (tj == 0) reds[w][r] = s;
        }
        __syncthreads();
#pragma unroll
        for (int r = 0; r < 8; ++r) {
            const float inv = 1.0f /
                (reds[0][r] + reds[1][r] + reds[2][r] + reds[3][r]);
            va[r][0] *= inv; va[r][1] *= inv;
            adjw[(size_t)(gR0 + r) * NN + 128 * w + tj]      = va[r][0];
            adjw[(size_t)(gR0 + r) * NN + 128 * w + 64 + tj] = va[r][1];
        }
    } else {
#pragma unroll
        for (int r = 0; r < 8; ++r) {
            va[r][0] = adjw[(size_t)(gR0 + r) * NN + 128 * w + tj];
            va[r][1] = adjw[(size_t)(gR0 + r) * NN + 128 * w + 64 + tj];
        }
    }

    //=== phase A: m partials (wave: all 8 rows x its 128-j quarter) =========
    {
        const float* hq = h_in + ((size_t)b * NN + 128 * w) * HH + tj;
        float mac[8] = {0.f, 0.f, 0.f, 0.f, 0.f, 0.f, 0.f, 0.f};
#pragma unroll
        for (int c = 0; c < 2; ++c) {
#pragma unroll 4
            for (int jj = 0; jj < 64; jj += 4) {
                const float h0 = hq[(64 * c + jj + 0) * HH];
                const float h1 = hq[(64 * c + jj + 1) * HH];
                const float h2 = hq[(64 * c + jj + 2) * HH];
                const float h3 = hq[(64 * c + jj + 3) * HH];
#pragma unroll
                for (int r = 0; r < 8; ++r) {
                    float a = fmaf(lane_bcast(va[r][c], jj + 0), h0, mac[r]);
                    a = fmaf(lane_bcast(va[r][c], jj + 1), h1, a);
                    a = fmaf(lane_bcast(va[r][c], jj + 2), h2, a);
                    mac[r] = fmaf(lane_bcast(va[r][c], jj + 3), h3, a);
                }
            }
        }
        if (MODE == 0) __syncthreads();   // zjs fully dead before red overlay
#pragma unroll
        for (int r = 0; r < 8; ++r) RED(w, r, tj) = mac[r];
    }
    __syncthreads();

    //=== phase B: wave w owns rows r0,r1: m reduce + mm GEMM (readlane) =====
    float mm0, mm1;
    {
        const float m0 = RED(0, r0, tj) + RED(1, r0, tj) + RED(2, r0, tj) + RED(3, r0, tj);
        const float m1 = RED(0, r1, tj) + RED(1, r1, tj) + RED(2, r1, tj) + RED(3, r1, tj);
        mm0 = bmsg[tj]; mm1 = mm0;
#pragma unroll 8
        for (int k = 0; k < HH; ++k) {
            const float wm = Wmsg[k * HH + tj];
            mm0 = fmaf(lane_bcast(m0, k), wm, mm0);
            mm1 = fmaf(lane_bcast(m1, k), wm, mm1);
        }
        mm0 = fmaxf(mm0, 0.f); mm1 = fmaxf(mm1, 0.f);
        mml[r0][tj] = mm0; mml[r1][tj] = mm1;
    }
    __syncthreads();   // mml ready; RED dead -> gpart overlay legal

    //=== phase C: wave = (half=gi/gh, kh=k-half): 3 gates x 8 rows x 32 k ===
    {
        const int half = w >> 1, kh = w & 1;
        const float* Wg = half ? Whh : Wih;
        const float* bg = half ? bhh : bih;
        float sreg[8];
#pragma unroll
        for (int r = 0; r < 8; ++r) sreg[r] = half ? hol[r][tj] : mml[r][tj];
        float g0[8], g1[8], g2[8];
#pragma unroll
        for (int r = 0; r < 8; ++r) {
            g0[r] = kh ? 0.f : bg[tj];
            g1[r] = kh ? 0.f : bg[64 + tj];
            g2[r] = kh ? 0.f : bg[128 + tj];
        }
        const int k0 = kh * 32;
#pragma unroll 4
        for (int kk = 0; kk < 32; ++kk) {
            const float* wk = Wg + (size_t)(k0 + kk) * 192;
            const float w0 = wk[tj], w1 = wk[64 + tj], w2 = wk[128 + tj];
#pragma unroll
            for (int r = 0; r < 8; ++r) {
                const float s = lane_bcast(sreg[r], k0 + kk);
                g0[r] = fmaf(s, w0, g0[r]);
                g1[r] = fmaf(s, w1, g1[r]);
                g2[r] = fmaf(s, w2, g2[r]);
            }
        }
#pragma unroll
        for (int r = 0; r < 8; ++r) {
            GP(half, kh, r, 0, tj) = g0[r];
            GP(half, kh, r, 1, tj) = g1[r];
            GP(half, kh, r, 2, tj) = g2[r];
        }
    }
    __syncthreads();

    //=== finalize: wave w rows r0,r1: GRU + store ===========================
    float hs0 = 0.f, hs1 = 0.f;
#pragma unroll
    for (int p = 0; p < 2; ++p) {
        const int rr = p ? r1 : r0;
        const float ir  = GP(0, 0, rr, 0, tj) + GP(0, 1, rr, 0, tj);
        const float iz  = GP(0, 0, rr, 1, tj) + GP(0, 1, rr, 1, tj);
        const float inn = GP(0, 0, rr, 2, tj) + GP(0, 1, rr, 2, tj);
        const float hr  = GP(1, 0, rr, 0, tj) + GP(1, 1, rr, 0, tj);
        const float hz  = GP(1, 0, rr, 1, tj) + GP(1, 1, rr, 1, tj);
        const float hn  = GP(1, 0, rr, 2, tj) + GP(1, 1, rr, 2, tj);
        const float rg = 1.f / (1.f + __expf(-(ir + hr)));
        const float zg = 1.f / (1.f + __expf(-(iz + hz)));
        const float ng = tanhf(inn + rg * hn);
        const float hnew = (1.f - zg) * ng + zg * hol[rr][tj];
        h_out[(size_t)(gR0 + rr) * HH + tj] = hnew;
        if (p) hs1 = hnew; else hs0 = hnew;
    }

    if (MODE == 1) {   // fold readout partial: block sum of its 8 rows
        __syncthreads();                  // mml dead
        mml[r0][tj] = hs0; mml[r1][tj] = hs1;
        __syncthreads();
        if (w == 0) {
            float s = 0.f;
#pragma unroll
            for (int r = 0; r < 8; ++r) s += mml[r][tj];
            partial[blockIdx.x * 64 + tj] = s;
        }
    }
#undef RED
#undef GP
}

// ---------------------------------------------------------------------------
// readout: out[b] = (sum of 64 tile-partials)/N @ W_out + b_out.
// ---------------------------------------------------------------------------
__global__ __launch_bounds__(64) void readout_kernel(
    const float* __restrict__ partial, const float* __restrict__ W_out,
    const float* __restrict__ b_out, float* __restrict__ out)
{
    const int b = blockIdx.x;
    const int hh = threadIdx.x;
    float s = 0.f;
#pragma unroll 8
    for (int c = 0; c < 64; ++c)
        s += partial[(b * 64 + c) * 64 + hh];
    float v = s * (1.0f / NN) * W_out[hh];
#pragma unroll
    for (int off = 32; off >= 1; off >>= 1) v += __shfl_xor(v, off);
    if (hh == 0) out[b] = v + b_out[0];
}

extern "C" void kernel_launch(void* const* d_in, const int* in_sizes, int n_in,
                              void* d_out, int out_size, void* d_ws, size_t ws_size,
                              hipStream_t stream)
{
    const float* x     = (const float*)d_in[0];
    const float* W_enc = (const float*)d_in[1];
    const float* b_enc = (const float*)d_in[2];
    const float* W_e1  = (const float*)d_in[3];
    const float* b_e1  = (const float*)d_in[4];
    const float* W_e2  = (const float*)d_in[5];
    const float* b_e2  = (const float*)d_in[6];
    const float* W_msg = (const float*)d_in[7];
    const float* b_msg = (const float*)d_in[8];
    const float* W_ih  = (const float*)d_in[9];
    const float* b_ih  = (const float*)d_in[10];
    const float* W_hh  = (const float*)d_in[11];
    const float* b_hh  = (const float*)d_in[12];
    const float* W_out = (const float*)d_in[13];
    const float* b_out = (const float*)d_in[14];
    float* out = (float*)d_out;

    float* ws  = (float*)d_ws;
    float* h0  = ws;
    float* h1  = h0 + BB * NN * HH;
    float* zi  = h1 + BB * NN * HH;
    float* zj  = zi + BB * NN * HH;
    float* prt = zj + BB * NN * HH;         // 512*64 partials
    float* adjw = prt + 512 * 64;

    encode_kernel<<<BB * NN / 4, 256, 0, stream>>>(x, W_enc, b_enc, W_e1, b_e1, h0, zi, zj);

    adjlayer_kernel<0><<<BB * (NN / 8), 256, 0, stream>>>(
        zi, zj, W_e2, b_e2, adjw, h0,
        W_msg, b_msg, W_ih, b_ih, W_hh, b_hh, h1, nullptr);
    adjlayer_kernel<1><<<BB * (NN / 8), 256, 0, stream>>>(
        zi, zj, W_e2, b_e2, adjw, h1,
        W_msg + HH * HH, b_msg + HH,
        W_ih + HH * 3 * HH, b_ih + 3 * HH, W_hh + HH * 3 * HH, b_hh + 3 * HH,
        h0, prt);

    readout_kernel<<<BB, 64, 0, stream>>>(prt, W_out, b_out, out);
}

// Round 11
// 73.254 us; speedup vs baseline: 1.1320x; 1.1320x over previous
//
#include <hip/hip_runtime.h>
#include <math.h>

#define BB 8
#define NN 512
#define FF 32
#define HH 64
#define NEG_BIG (-1.0e30f)

__device__ __forceinline__ float lane_bcast(float v, int l) {
    return __int_as_float(__builtin_amdgcn_readlane(__float_as_int(v), l));
}

// ---------------------------------------------------------------------------
// encode: h = relu(x@W_enc+b); zi = h@W_e1[:H]+b_e1 (folded); zjT = transposed
// (h@W_e1[H:]) so the adj kernel can load zj with lane=j COALESCED.
// grid 1024 x 256: block = 4 rows, wave qu owns row, lane hh owns column.
// ---------------------------------------------------------------------------
__global__ __launch_bounds__(256) void encode_kernel(
    const float* __restrict__ x, const float* __restrict__ W_enc,
    const float* __restrict__ b_enc, const float* __restrict__ W_e1,
    const float* __restrict__ b_e1,
    float* __restrict__ h, float* __restrict__ zi, float* __restrict__ zjT)
{
    const int t = threadIdx.x;
    const int hh = t & 63;
    const int qu = __builtin_amdgcn_readfirstlane(t >> 6);
    const int gR = blockIdx.x * 4 + qu;           // 0..B*N-1

    const float xv = x[gR * FF + (hh & 31)];      // coalesced; lanes 32+ dup
    float acc = b_enc[hh];
#pragma unroll 8
    for (int k = 0; k < FF; ++k)
        acc = fmaf(lane_bcast(xv, k), W_enc[k * HH + hh], acc);
    const float hval = fmaxf(acc, 0.f);
    h[gR * HH + hh] = hval;

    float z1 = b_e1[hh], z2 = 0.f;
#pragma unroll 8
    for (int k = 0; k < HH; ++k) {
        const float hk = lane_bcast(hval, k);
        z1 = fmaf(hk, W_e1[k * HH + hh], z1);
        z2 = fmaf(hk, W_e1[(HH + k) * HH + hh], z2);
    }
    zi[gR * HH + hh] = z1;
    // transpose scatter: zjT[b][k=hh][n]
    zjT[((size_t)(gR >> 9) * HH + hh) * NN + (gR & (NN - 1))] = z2;
}

// ---------------------------------------------------------------------------
// adjlayer<MODE>: 512 blocks x 512 thr (8 waves; 2 blocks/CU = 4 waves/SIMD).
// block = (b, 8 rows); wave w owns j-slice [64w,64w+64) and row w.
// MODE 0 edge phase: lane tj = j: zjT loads coalesced into regs; zi & W_e2
//   are BLOCK-UNIFORM -> s_load (SGPR operands, zero VALU cost); inner body
//   is exactly 3 VALU per edge term. No LDS staging, no readlane.
// Phase A: m partials via readlane(va)+fma, RED in LDS.
// Phase B: wave w = row w: mm = relu(m@Wmsg+b) via readlane.
// Phase C: wave = (half,kh,rq): 3 gates x 4 rows x 32 k -> partials in GP.
// ---------------------------------------------------------------------------
template <int MODE>
__global__ __launch_bounds__(512, 4) void adjlayer_kernel(
    const float* __restrict__ zi, const float* __restrict__ zjT,
    const float* __restrict__ We2, const float* __restrict__ be2,
    float* __restrict__ adjw, const float* __restrict__ h_in,
    const float* __restrict__ Wmsg, const float* __restrict__ bmsg,
    const float* __restrict__ Wih, const float* __restrict__ bih,
    const float* __restrict__ Whh, const float* __restrict__ bhh,
    float* __restrict__ h_out, float* __restrict__ partial)
{
    const int b  = blockIdx.x >> 6;
    const int i0 = (blockIdx.x & 63) << 3;        // 8 rows
    const int t  = threadIdx.x;
    const int tj = t & 63;
    const int w  = __builtin_amdgcn_readfirstlane(t >> 6);   // 0..7
    const int gR0 = b * NN + i0;
    const int j   = 64 * w + tj;                  // this lane's j position

    __shared__ float smem[6336];                  // union RED(4224f)/GP(6336f)
    __shared__ float mml[8][66];
    __shared__ float hol[8][66];
    __shared__ float redm[8][8];
    __shared__ float reds[8][8];
#define RED(p, r, c)        smem[(((p) * 8) + (r)) * 66 + (c)]
#define GP(h2, k2, r, g, c) smem[(((((h2) * 2 + (k2)) * 8 + (r)) * 3 + (g)) * 66) + (c)]

    hol[w][tj] = h_in[(size_t)(gR0 + w) * HH + tj];

    //=== adjacency row-slice in registers: va[r] = adj[i0+r][j] =============
    float va[8];
    if (MODE == 0) {
        const float* zib = zi + (size_t)gR0 * HH;          // uniform -> s_load
        const float* ztb = zjT + (size_t)b * HH * NN + j;  // lane-coalesced
        const float bias2 = be2[0];
        float acc[8];
#pragma unroll
        for (int r = 0; r < 8; ++r) acc[r] = bias2;

        for (int kc = 0; kc < 8; ++kc) {
            float zt[8];
#pragma unroll
            for (int kk = 0; kk < 8; ++kk)
                zt[kk] = ztb[(size_t)(kc * 8 + kk) * NN];
#pragma unroll
            for (int kk = 0; kk < 8; ++kk) {
                const int k = kc * 8 + kk;
                const float wk = We2[k];                   // s_load
#pragma unroll
                for (int r = 0; r < 8; ++r) {
                    const float zv = zib[r * HH + k];      // s_load
                    acc[r] = fmaf(fmaxf(zv + zt[kk], 0.f), wk, acc[r]);
                }
            }
        }
#pragma unroll
        for (int r = 0; r < 8; ++r)
            if (j == i0 + r) acc[r] = NEG_BIG;             // diag mask

        // softmax: in-wave shfl + cross-wave LDS reduce
#pragma unroll
        for (int r = 0; r < 8; ++r) {
            float m = acc[r];
#pragma unroll
            for (int off = 32; off >= 1; off >>= 1) m = fmaxf(m, __shfl_xor(m, off));
            if (tj == 0) redm[w][r] = m;
        }
        __syncthreads();
        float M[8];
#pragma unroll
        for (int r = 0; r < 8; ++r) {
            float m = redm[0][r];
#pragma unroll
            for (int p = 1; p < 8; ++p) m = fmaxf(m, redm[p][r]);
            M[r] = m;
        }
#pragma unroll
        for (int r = 0; r < 8; ++r) {
            const float e = __expf(acc[r] - M[r]);
            va[r] = e;
            float s = e;
#pragma unroll
            for (int off = 32; off >= 1; off >>= 1) s += __shfl_xor(s, off);
            if (tj == 0) reds[w][r] = s;
        }
        __syncthreads();
#pragma unroll
        for (int r = 0; r < 8; ++r) {
            float s = reds[0][r];
#pragma unroll
            for (int p = 1; p < 8; ++p) s += reds[p][r];
            va[r] *= 1.0f / s;
            adjw[(size_t)(gR0 + r) * NN + j] = va[r];
        }
    } else {
#pragma unroll
        for (int r = 0; r < 8; ++r)
            va[r] = adjw[(size_t)(gR0 + r) * NN + j];
    }

    //=== phase A: m partials (wave w covers its 64-j slice, all 8 rows) =====
    {
        const float* hq = h_in + ((size_t)b * NN + 64 * w) * HH + tj;
        float mac[8] = {0.f, 0.f, 0.f, 0.f, 0.f, 0.f, 0.f, 0.f};
#pragma unroll 4
        for (int jj = 0; jj < 64; ++jj) {
            const float hv = hq[(size_t)jj * HH];
#pragma unroll
            for (int r = 0; r < 8; ++r)
                mac[r] = fmaf(lane_bcast(va[r], jj), hv, mac[r]);
        }
#pragma unroll
        for (int r = 0; r < 8; ++r) RED(w, r, tj) = mac[r];
    }
    __syncthreads();

    //=== phase B: wave w = row w: m reduce + mm GEMM ========================
    {
        float m = RED(0, w, tj);
#pragma unroll
        for (int p = 1; p < 8; ++p) m += RED(p, w, tj);
        float mmv = bmsg[tj];
#pragma unroll 8
        for (int k = 0; k < HH; ++k)
            mmv = fmaf(lane_bcast(m, k), Wmsg[k * HH + tj], mmv);
        mml[w][tj] = fmaxf(mmv, 0.f);
    }
    __syncthreads();   // mml ready; RED dead -> GP overlay legal

    //=== phase C: wave = (half, kh, rq): 3 gates x 4 rows x 32 k ============
    {
        const int half = w >> 2, kh = (w >> 1) & 1, rq = w & 1;
        const float* Wg = half ? Whh : Wih;
        const float* bg = half ? bhh : bih;
        float sreg[4];
#pragma unroll
        for (int r = 0; r < 4; ++r)
            sreg[r] = half ? hol[rq * 4 + r][tj] : mml[rq * 4 + r][tj];
        float g0[4], g1[4], g2[4];
#pragma unroll
        for (int r = 0; r < 4; ++r) {
            g0[r] = kh ? 0.f : bg[tj];
            g1[r] = kh ? 0.f : bg[64 + tj];
            g2[r] = kh ? 0.f : bg[128 + tj];
        }
        const int k0 = kh * 32;
#pragma unroll 4
        for (int kk = 0; kk < 32; ++kk) {
            const float* wk = Wg + (size_t)(k0 + kk) * 192;
            const float w0 = wk[tj], w1 = wk[64 + tj], w2 = wk[128 + tj];
#pragma unroll
            for (int r = 0; r < 4; ++r) {
                const float s = lane_bcast(sreg[r], k0 + kk);
                g0[r] = fmaf(s, w0, g0[r]);
                g1[r] = fmaf(s, w1, g1[r]);
                g2[r] = fmaf(s, w2, g2[r]);
            }
        }
#pragma unroll
        for (int r = 0; r < 4; ++r) {
            GP(half, kh, rq * 4 + r, 0, tj) = g0[r];
            GP(half, kh, rq * 4 + r, 1, tj) = g1[r];
            GP(half, kh, rq * 4 + r, 2, tj) = g2[r];
        }
    }
    __syncthreads();

    //=== finalize: wave w = row w ===========================================
    float hnew;
    {
        const float ir  = GP(0, 0, w, 0, tj) + GP(0, 1, w, 0, tj);
        const float iz  = GP(0, 0, w, 1, tj) + GP(0, 1, w, 1, tj);
        const float inn = GP(0, 0, w, 2, tj) + GP(0, 1, w, 2, tj);
        const float hr  = GP(1, 0, w, 0, tj) + GP(1, 1, w, 0, tj);
        const float hz  = GP(1, 0, w, 1, tj) + GP(1, 1, w, 1, tj);
        const float hn  = GP(1, 0, w, 2, tj) + GP(1, 1, w, 2, tj);
        const float rg = 1.f / (1.f + __expf(-(ir + hr)));
        const float zg = 1.f / (1.f + __expf(-(iz + hz)));
        const float ng = tanhf(inn + rg * hn);
        hnew = (1.f - zg) * ng + zg * hol[w][tj];
        h_out[(size_t)(gR0 + w) * HH + tj] = hnew;
    }

    if (MODE == 1) {   // fold readout partial: block sum of its 8 rows
        __syncthreads();                  // mml dead (phase C reads done)
        mml[w][tj] = hnew;
        __syncthreads();
        if (w == 0) {
            float s = 0.f;
#pragma unroll
            for (int r = 0; r < 8; ++r) s += mml[r][tj];
            partial[blockIdx.x * 64 + tj] = s;
        }
    }
#undef RED
#undef GP
}

// ---------------------------------------------------------------------------
// readout: out[b] = (sum of 64 tile-partials)/N @ W_out + b_out.
// ---------------------------------------------------------------------------
__global__ __launch_bounds__(64) void readout_kernel(
    const float* __restrict__ partial, const float* __restrict__ W_out,
    const float* __restrict__ b_out, float* __restrict__ out)
{
    const int b = blockIdx.x;
    const int hh = threadIdx.x;
    float s = 0.f;
#pragma unroll 8
    for (int c = 0; c < 64; ++c)
        s += partial[(b * 64 + c) * 64 + hh];
    float v = s * (1.0f / NN) * W_out[hh];
#pragma unroll
    for (int off = 32; off >= 1; off >>= 1) v += __shfl_xor(v, off);
    if (hh == 0) out[b] = v + b_out[0];
}

extern "C" void kernel_launch(void* const* d_in, const int* in_sizes, int n_in,
                              void* d_out, int out_size, void* d_ws, size_t ws_size,
                              hipStream_t stream)
{
    const float* x     = (const float*)d_in[0];
    const float* W_enc = (const float*)d_in[1];
    const float* b_enc = (const float*)d_in[2];
    const float* W_e1  = (const float*)d_in[3];
    const float* b_e1  = (const float*)d_in[4];
    const float* W_e2  = (const float*)d_in[5];
    const float* b_e2  = (const float*)d_in[6];
    const float* W_msg = (const float*)d_in[7];
    const float* b_msg = (const float*)d_in[8];
    const float* W_ih  = (const float*)d_in[9];
    const float* b_ih  = (const float*)d_in[10];
    const float* W_hh  = (const float*)d_in[11];
    const float* b_hh  = (const float*)d_in[12];
    const float* W_out = (const float*)d_in[13];
    const float* b_out = (const float*)d_in[14];
    float* out = (float*)d_out;

    float* ws   = (float*)d_ws;
    float* h0   = ws;
    float* h1   = h0 + BB * NN * HH;
    float* zi   = h1 + BB * NN * HH;
    float* zjT  = zi + BB * NN * HH;        // [B][H][N]
    float* prt  = zjT + BB * HH * NN;       // 512*64 partials
    float* adjw = prt + 512 * 64;

    encode_kernel<<<BB * NN / 4, 256, 0, stream>>>(x, W_enc, b_enc, W_e1, b_e1, h0, zi, zjT);

    adjlayer_kernel<0><<<BB * (NN / 8), 512, 0, stream>>>(
        zi, zjT, W_e2, b_e2, adjw, h0,
        W_msg, b_msg, W_ih, b_ih, W_hh, b_hh, h1, nullptr);
    adjlayer_kernel<1><<<BB * (NN / 8), 512, 0, stream>>>(
        zi, zjT, W_e2, b_e2, adjw, h1,
        W_msg + HH * HH, b_msg + HH,
        W_ih + HH * 3 * HH, b_ih + 3 * HH, W_hh + HH * 3 * HH, b_hh + 3 * HH,
        h0, prt);

    readout_kernel<<<BB, 64, 0, stream>>>(prt, W_out, b_out, out);
}